// Round 3
// baseline (2600.161 us; speedup 1.0000x reference)
//
#include <hip/hip_runtime.h>

// GatherModel: 6-step NNConv message passing, reformulated:
//   agg[n,o] = sum_{k,i} S[n,k,i] * T'[k,i,o]
//   S[n] = sum_{e: dst=n} h'[e] (x) out[src[e]]     (rank-1 outer products)
//   h'[e] = [relu(e_feat@en_w1+b1), 1]              (step-invariant, bias folded)
//   T'[k,i,o] = en_w2[k, i*42+o]; T'[42,i,o] = en_b2[i*42+o]
// R3: (a) k_agg_part T-loads forced scalar (readfirstlane -> s_load_dwordx4),
//     (b) aggP replaced by fp32 atomics into one agg buffer,
//     (c) edges pre-permuted (h_perm, srcp) so k_S streams sequentially,
//     (d) k_S split 2 waves/node (k-halves) + x prefetch.

#define N_NODES 10000
#define N_EDGES 160000
#define D 42
#define DE 10
#define KH 43          // 42 + bias row
#define HP 44          // h row stride (11 x float4)
#define KI 1806        // 43*42
#define SP 1808        // S / T2t row stride
#define KSPLIT 12
#define KRANGE 152     // 11*152 + 136 = 1808, %4==0
#define MB 64          // nodes per WG in k_agg_part / k_node

__global__ __launch_bounds__(256) void k_lin0(const float* __restrict__ nf,
        const float* __restrict__ w, const float* __restrict__ b,
        float* __restrict__ out) {
    int idx = blockIdx.x * 256 + threadIdx.x;
    if (idx >= N_NODES * D) return;
    int n = idx / D, j = idx % D;
    const float* row = nf + n * D;
    float acc = b[j];
    #pragma unroll
    for (int i = 0; i < D; ++i) acc = fmaf(row[i], w[i * D + j], acc);
    out[idx] = fmaxf(acc, 0.f);
}

// T2t[o][ki], ki = k*42+i: = en_w2[k*1764 + i*42 + o] (k<42), en_b2[i*42+o] (k==42)
__global__ __launch_bounds__(256) void k_T2t(const float* __restrict__ w2,
        const float* __restrict__ b2, float* __restrict__ T2t) {
    int idx = blockIdx.x * 256 + threadIdx.x;
    if (idx >= D * SP) return;
    int o = idx / SP, ki = idx % SP;
    float v = 0.f;
    if (ki < KI) {
        int k = ki / D, i = ki % D;
        v = (k < D) ? w2[k * (D * D) + i * D + o] : b2[i * D + o];
    }
    T2t[idx] = v;       // pad cols (1806,1807) = 0
}

__global__ __launch_bounds__(256) void k_hist(const int* __restrict__ dst,
        int* __restrict__ cnt) {
    int e = blockIdx.x * 256 + threadIdx.x;
    if (e < N_EDGES) atomicAdd(&cnt[dst[e]], 1);
}

__global__ __launch_bounds__(1024) void k_scan(const int* __restrict__ cnt,
        int* __restrict__ row_ptr, int* __restrict__ cursor) {
    __shared__ int buf[1024];
    __shared__ int s_run;
    const int t = threadIdx.x;
    if (t == 0) s_run = 0;
    __syncthreads();
    for (int base = 0; base < N_NODES; base += 1024) {
        int v = (base + t < N_NODES) ? cnt[base + t] : 0;
        buf[t] = v;
        __syncthreads();
        for (int off = 1; off < 1024; off <<= 1) {
            int add = (t >= off) ? buf[t - off] : 0;
            __syncthreads();
            buf[t] += add;
            __syncthreads();
        }
        int excl = buf[t] - v;
        if (base + t < N_NODES) {
            int val = s_run + excl;
            row_ptr[base + t] = val;
            cursor[base + t]  = val;
        }
        __syncthreads();
        if (t == 0) s_run += buf[1023];
        __syncthreads();
    }
    if (t == 0) { row_ptr[N_NODES] = s_run; cursor[N_NODES] = s_run; }
}

__global__ __launch_bounds__(256) void k_scatter(const int* __restrict__ dst,
        const int* __restrict__ src, int* __restrict__ cursor,
        int* __restrict__ srcp, int* __restrict__ pos) {
    int e = blockIdx.x * 256 + threadIdx.x;
    if (e < N_EDGES) {
        int p = atomicAdd(&cursor[dst[e]], 1);
        pos[e] = p;
        srcp[p] = src[e];
    }
}

// h' in permuted (CSR) order: h_perm[pos[e]] = [relu(ef@w1+b1), 1, 0]
__global__ __launch_bounds__(256) void k_h(const float* __restrict__ ef,
        const float* __restrict__ w1, const float* __restrict__ b1,
        const int* __restrict__ pos, float* __restrict__ hp) {
    int idx = blockIdx.x * 256 + threadIdx.x;
    if (idx >= N_EDGES * HP) return;
    int e = idx / HP, j = idx % HP;
    float v;
    if (j < D) {
        const float* row = ef + e * DE;
        float acc = b1[j];
        #pragma unroll
        for (int i = 0; i < DE; ++i) acc = fmaf(row[i], w1[i * D + j], acc);
        v = fmaxf(acc, 0.f);
    } else {
        v = (j == D) ? 1.0f : 0.0f;
    }
    hp[(size_t)pos[e] * HP + j] = v;
}

#define EDGE_FMA(M0, MC)                                                  \
    {                                                                     \
        const float4* hq = (const float4*)(hp + (size_t)ptr * HP);        \
        _Pragma("unroll")                                                 \
        for (int m = 0; m < (MC); ++m) {                                  \
            float4 q = hq[(M0) + m];                                      \
            acc[4 * m + 0] = fmaf(q.x, x, acc[4 * m + 0]);                \
            acc[4 * m + 1] = fmaf(q.y, x, acc[4 * m + 1]);                \
            acc[4 * m + 2] = fmaf(q.z, x, acc[4 * m + 2]);                \
            acc[4 * m + 3] = fmaf(q.w, x, acc[4 * m + 3]);                \
        }                                                                 \
    }

// 2 waves per node (k-halves): half0 -> k 0..23, half1 -> k 24..42 (+pads).
// hp/srcp reads are sequential streams; x gather prefetched one edge ahead.
__global__ __launch_bounds__(256) void k_S(
        const float* __restrict__ hp, const float* __restrict__ out_in,
        const int* __restrict__ srcp, const int* __restrict__ row_ptr,
        float* __restrict__ S) {
    const int wv = __builtin_amdgcn_readfirstlane(threadIdx.x >> 6);
    const int node = blockIdx.x * 2 + (wv >> 1);
    const int half = wv & 1;
    const int l = threadIdx.x & 63;
    float acc[24];
    #pragma unroll
    for (int i = 0; i < 24; ++i) acc[i] = 0.f;
    const int beg = row_ptr[node], end = row_ptr[node + 1];
    float x = 0.f;
    if (beg < end) {
        int s0 = srcp[beg];
        x = (l < D) ? out_in[s0 * D + l] : 0.f;
    }
    for (int ptr = beg; ptr < end; ++ptr) {
        float x2 = 0.f;
        if (ptr + 1 < end) {
            int s2 = srcp[ptr + 1];
            x2 = (l < D) ? out_in[s2 * D + l] : 0.f;
        }
        if (half == 0) {
            EDGE_FMA(0, 6)
        } else {
            EDGE_FMA(6, 5)
        }
        x = x2;
    }
    if (l < D) {
        if (half == 0) {
            #pragma unroll
            for (int r = 0; r < 24; ++r)          // k = 0..23
                S[(size_t)node * SP + r * D + l] = acc[r];
        } else {
            #pragma unroll
            for (int r = 0; r < 19; ++r)          // k = 24..42 (skip pad k=43)
                S[(size_t)node * SP + (24 + r) * D + l] = acc[r];
        }
    } else if (half == 1 && l < D + 2) {
        S[(size_t)node * SP + KI + (l - D)] = 0.f;  // zero pad cols
    }
}

// Partial GEMM, K-split: acc over [kbeg,kend), atomically added into agg.
// T2t loads are wave-uniform (w via readfirstlane) -> s_load on the SMEM pipe.
__global__ __launch_bounds__(256) void k_agg_part(
        const float* __restrict__ S, const float* __restrict__ T2t,
        float* __restrict__ agg) {
    const int nl = threadIdx.x & 63;
    const int w  = __builtin_amdgcn_readfirstlane(threadIdx.x >> 6);
    const int n  = blockIdx.x * MB + nl;
    const int kbeg = blockIdx.y * KRANGE;
    const int kend = min(kbeg + KRANGE, SP);
    float acc[11];
    #pragma unroll
    for (int j = 0; j < 11; ++j) acc[j] = 0.f;
    // OOB lanes (n>=N_NODES, last block) read a few hundred KB past Sbuf —
    // still inside ws (agg region), finite floats; results are discarded.
    const float* srow = S + (size_t)n * SP;
    for (int ki = kbeg; ki < kend; ki += 4) {
        float4 s4 = *(const float4*)(srow + ki);
        #pragma unroll
        for (int j = 0; j < 11; ++j) {
            if (w + 4 * j < D) {                 // uniform (w scalar)
                float4 t4 = *(const float4*)(T2t + (w + 4 * j) * SP + ki);
                acc[j] += s4.x * t4.x + s4.y * t4.y + s4.z * t4.z + s4.w * t4.w;
            }
        }
    }
    if (n < N_NODES) {
        #pragma unroll
        for (int j = 0; j < 11; ++j)
            if (w + 4 * j < D)
                unsafeAtomicAdd(&agg[(size_t)n * D + w + 4 * j], acc[j]);
    }
}

// Epilogue: m = relu(agg + out_in + conv_b); out' = relu(m@msg_w + msg_b) [+nf]
__global__ __launch_bounds__(256) void k_node(
        const float* __restrict__ agg, const float* __restrict__ out_in,
        const float* __restrict__ nf, const float* __restrict__ msg_w,
        const float* __restrict__ msg_b, const float* __restrict__ conv_b,
        float* __restrict__ out_dst, int last) {
    __shared__ float s_m[MB * 45];               // stride 45: conflict-free
    const int nl = threadIdx.x & 63;
    const int w  = __builtin_amdgcn_readfirstlane(threadIdx.x >> 6);
    const int n  = blockIdx.x * MB + nl;
    const int jm = (w < 2) ? 11 : 10;

    if (n < N_NODES) {
        for (int j = 0; j < jm; ++j) {
            int o = w + 4 * j;
            float m = agg[(size_t)n * D + o] + out_in[n * D + o] + conv_b[o];
            s_m[nl * 45 + o] = fmaxf(m, 0.f);
        }
    }
    __syncthreads();
    if (n < N_NODES) {
        float a2[11];
        #pragma unroll
        for (int j = 0; j < 11; ++j) a2[j] = 0.f;
        for (int o2 = 0; o2 < D; ++o2) {
            float mv = s_m[nl * 45 + o2];
            #pragma unroll
            for (int j = 0; j < 11; ++j)
                if (w + 4 * j < D)
                    a2[j] = fmaf(mv, msg_w[o2 * D + w + 4 * j], a2[j]);
        }
        for (int j = 0; j < 11; ++j) {
            if (w + 4 * j < D) {
                int p = w + 4 * j;
                float v = fmaxf(a2[j] + msg_b[p], 0.f);
                if (last) v += nf[n * D + p];
                out_dst[n * D + p] = v;
            }
        }
    }
}

extern "C" void kernel_launch(void* const* d_in, const int* in_sizes, int n_in,
                              void* d_out, int out_size, void* d_ws, size_t ws_size,
                              hipStream_t stream) {
    const float* nf    = (const float*)d_in[0];
    const float* ef    = (const float*)d_in[1];
    const int*   src   = (const int*)d_in[2];
    const int*   dst   = (const int*)d_in[3];
    const float* lin0w = (const float*)d_in[4];
    const float* lin0b = (const float*)d_in[5];
    const float* msgw  = (const float*)d_in[6];
    const float* msgb  = (const float*)d_in[7];
    const float* enw1  = (const float*)d_in[8];
    const float* enb1  = (const float*)d_in[9];
    const float* enw2  = (const float*)d_in[10];
    const float* enb2  = (const float*)d_in[11];
    const float* convb = (const float*)d_in[12];

    // ws layout (~107 MB)
    char* p = (char*)d_ws;
    auto alloc = [&](size_t bytes) -> char* {
        char* r = p; p += (bytes + 255) & ~(size_t)255; return r;
    };
    float* outA = (float*)alloc((size_t)N_NODES * D * 4);
    float* outB = (float*)alloc((size_t)N_NODES * D * 4);
    float* hp   = (float*)alloc((size_t)N_EDGES * HP * 4);
    float* T2t  = (float*)alloc((size_t)D * SP * 4);
    float* Sbuf = (float*)alloc((size_t)N_NODES * SP * 4);
    float* agg  = (float*)alloc((size_t)N_NODES * D * 4);   // also OOB-read pad
    int* cnt    = (int*)alloc((N_NODES + 1) * 4);
    int* rowp   = (int*)alloc((N_NODES + 1) * 4);
    int* cur    = (int*)alloc((N_NODES + 1) * 4);
    int* srcp   = (int*)alloc((size_t)N_EDGES * 4);
    int* posb   = (int*)alloc((size_t)N_EDGES * 4);

    hipMemsetAsync(cnt, 0, (N_NODES + 1) * 4, stream);
    k_lin0<<<(N_NODES * D + 255) / 256, 256, 0, stream>>>(nf, lin0w, lin0b, outA);
    k_T2t<<<(D * SP + 255) / 256, 256, 0, stream>>>(enw2, enb2, T2t);
    k_hist<<<(N_EDGES + 255) / 256, 256, 0, stream>>>(dst, cnt);
    k_scan<<<1, 1024, 0, stream>>>(cnt, rowp, cur);
    k_scatter<<<(N_EDGES + 255) / 256, 256, 0, stream>>>(dst, src, cur, srcp, posb);
    k_h<<<(N_EDGES * HP + 255) / 256, 256, 0, stream>>>(ef, enw1, enb1, posb, hp);

    const int ntiles = (N_NODES + MB - 1) / MB;   // 157
    float* bufs[2] = {outA, outB};
    for (int s_i = 0; s_i < 6; ++s_i) {
        const float* cin = bufs[s_i % 2];
        float* cout = bufs[(s_i + 1) % 2];
        int last = (s_i == 5) ? 1 : 0;
        k_S<<<N_NODES / 2, 256, 0, stream>>>(hp, cin, srcp, rowp, Sbuf);
        hipMemsetAsync(agg, 0, (size_t)N_NODES * D * 4, stream);
        k_agg_part<<<dim3(ntiles, KSPLIT), 256, 0, stream>>>(Sbuf, T2t, agg);
        k_node<<<ntiles, 256, 0, stream>>>(agg, cin, nf, msgw, msgb, convb,
                                           last ? (float*)d_out : cout, last);
    }
}

// Round 4
// 1314.240 us; speedup vs baseline: 1.9785x; 1.9785x over previous
//
#include <hip/hip_runtime.h>

// GatherModel: 6-step NNConv message passing, reformulated:
//   agg[n,o] = sum_{k,i} S[n,k,i] * T'[k,i,o]
//   S[n] = sum_{e: dst=n} h'[e] (x) out[src[e]]     (rank-1 outer products)
//   h'[e] = [relu(e_feat@en_w1+b1), 1]              (step-invariant, bias folded)
//   T'[k,i,o] = en_w2[k, i*42+o]; T'[42,i,o] = en_b2[i*42+o]
// R4: revert R3's atomics (157 MB/dispatch write-through!) and scalar T-loads
// (SMEM lgkmcnt(0) serialization). k_agg_part: 2 nodes/thread (2 independent
// S streams, 88 FMA : 13 VMEM), branch-free j-loop via 44-row padded T2t,
// partials + separate coalesced reduce. k_S: 1 wave/node, depth-2 x prefetch.

#define N_NODES 10000
#define N_EDGES 160000
#define D 42
#define DE 10
#define KH 43          // 42 + bias row
#define HP 44          // h row stride (11 x float4)
#define KI 1806        // 43*42
#define SP 1808        // S / T2t row stride
#define KSPLIT 12
#define KRANGE 152     // 11*152 + 136 = 1808, %4==0
#define MB2 128        // nodes per k_agg_part block (2 per thread)
#define NPAD 10112     // S rows padded to 79*128
#define MB 64          // nodes per k_out block

__global__ __launch_bounds__(256) void k_lin0(const float* __restrict__ nf,
        const float* __restrict__ w, const float* __restrict__ b,
        float* __restrict__ out) {
    int idx = blockIdx.x * 256 + threadIdx.x;
    if (idx >= N_NODES * D) return;
    int n = idx / D, j = idx % D;
    const float* row = nf + n * D;
    float acc = b[j];
    #pragma unroll
    for (int i = 0; i < D; ++i) acc = fmaf(row[i], w[i * D + j], acc);
    out[idx] = fmaxf(acc, 0.f);
}

// T2t[o][ki] padded to 44 rows; rows 42,43 = 0 and pad cols (1806,1807) = 0
__global__ __launch_bounds__(256) void k_T2t(const float* __restrict__ w2,
        const float* __restrict__ b2, float* __restrict__ T2t) {
    int idx = blockIdx.x * 256 + threadIdx.x;
    if (idx >= 44 * SP) return;
    int o = idx / SP, ki = idx % SP;
    float v = 0.f;
    if (ki < KI && o < D) {
        int k = ki / D, i = ki % D;
        v = (k < D) ? w2[k * (D * D) + i * D + o] : b2[i * D + o];
    }
    T2t[idx] = v;
}

__global__ __launch_bounds__(256) void k_hist(const int* __restrict__ dst,
        int* __restrict__ cnt) {
    int e = blockIdx.x * 256 + threadIdx.x;
    if (e < N_EDGES) atomicAdd(&cnt[dst[e]], 1);
}

__global__ __launch_bounds__(1024) void k_scan(const int* __restrict__ cnt,
        int* __restrict__ row_ptr, int* __restrict__ cursor) {
    __shared__ int buf[1024];
    __shared__ int s_run;
    const int t = threadIdx.x;
    if (t == 0) s_run = 0;
    __syncthreads();
    for (int base = 0; base < N_NODES; base += 1024) {
        int v = (base + t < N_NODES) ? cnt[base + t] : 0;
        buf[t] = v;
        __syncthreads();
        for (int off = 1; off < 1024; off <<= 1) {
            int add = (t >= off) ? buf[t - off] : 0;
            __syncthreads();
            buf[t] += add;
            __syncthreads();
        }
        int excl = buf[t] - v;
        if (base + t < N_NODES) {
            int val = s_run + excl;
            row_ptr[base + t] = val;
            cursor[base + t]  = val;
        }
        __syncthreads();
        if (t == 0) s_run += buf[1023];
        __syncthreads();
    }
    if (t == 0) { row_ptr[N_NODES] = s_run; cursor[N_NODES] = s_run; }
}

__global__ __launch_bounds__(256) void k_scatter(const int* __restrict__ dst,
        const int* __restrict__ src, int* __restrict__ cursor,
        int* __restrict__ srcp, int* __restrict__ pos) {
    int e = blockIdx.x * 256 + threadIdx.x;
    if (e < N_EDGES) {
        int p = atomicAdd(&cursor[dst[e]], 1);
        pos[e] = p;
        srcp[p] = src[e];
    }
}

// h' in permuted (CSR) order: hp[pos[e]] = [relu(ef@w1+b1), 1, 0]
__global__ __launch_bounds__(256) void k_h(const float* __restrict__ ef,
        const float* __restrict__ w1, const float* __restrict__ b1,
        const int* __restrict__ pos, float* __restrict__ hp) {
    int idx = blockIdx.x * 256 + threadIdx.x;
    if (idx >= N_EDGES * HP) return;
    int e = idx / HP, j = idx % HP;
    float v;
    if (j < D) {
        const float* row = ef + e * DE;
        float acc = b1[j];
        #pragma unroll
        for (int i = 0; i < DE; ++i) acc = fmaf(row[i], w1[i * D + j], acc);
        v = fmaxf(acc, 0.f);
    } else {
        v = (j == D) ? 1.0f : 0.0f;
    }
    hp[(size_t)pos[e] * HP + j] = v;
}

// One wave per node: acc[44] in registers, lane = column i.
// hp reads are a sequential stream; x gather software-pipelined depth 2.
__global__ __launch_bounds__(256) void k_S(
        const float* __restrict__ hp, const float* __restrict__ out_in,
        const int* __restrict__ srcp, const int* __restrict__ row_ptr,
        float* __restrict__ S) {
    const int node = blockIdx.x * 4 + (threadIdx.x >> 6);
    const int l = threadIdx.x & 63;
    const bool act = (l < D);
    float acc[HP];
    #pragma unroll
    for (int k = 0; k < HP; ++k) acc[k] = 0.f;
    const int beg = row_ptr[node], end = row_ptr[node + 1];
    float x0 = 0.f, x1 = 0.f;
    if (beg < end && act)     x0 = out_in[srcp[beg] * D + l];
    if (beg + 1 < end && act) x1 = out_in[srcp[beg + 1] * D + l];
    for (int p = beg; p < end; ++p) {
        float xn = 0.f;
        if (p + 2 < end && act) xn = out_in[srcp[p + 2] * D + l];
        const float4* hq = (const float4*)(hp + (size_t)p * HP);
        #pragma unroll
        for (int m = 0; m < HP / 4; ++m) {
            float4 q = hq[m];
            acc[4 * m + 0] = fmaf(q.x, x0, acc[4 * m + 0]);
            acc[4 * m + 1] = fmaf(q.y, x0, acc[4 * m + 1]);
            acc[4 * m + 2] = fmaf(q.z, x0, acc[4 * m + 2]);
            acc[4 * m + 3] = fmaf(q.w, x0, acc[4 * m + 3]);
        }
        x0 = x1; x1 = xn;
    }
    if (act) {
        #pragma unroll
        for (int k = 0; k < KH; ++k)
            S[(size_t)node * SP + k * D + l] = acc[k];
    }
}

// Partial GEMM: aggP[ks][n][o] = sum_{ki in split} S[n][ki] * T2t[o][ki]
// 2 nodes per thread (nl, nl+64): two independent S streams per T-load.
__global__ __launch_bounds__(256) void k_agg_part(
        const float* __restrict__ S, const float* __restrict__ T2t,
        float* __restrict__ aggP) {
    const int nl = threadIdx.x & 63;
    const int w  = threadIdx.x >> 6;            // o = w + 4j
    const int n0 = blockIdx.x * MB2 + nl;
    const int n1 = n0 + 64;
    const int kbeg = blockIdx.y * KRANGE;
    const int kend = min(kbeg + KRANGE, SP);

    float acc0[11], acc1[11];
    #pragma unroll
    for (int j = 0; j < 11; ++j) { acc0[j] = 0.f; acc1[j] = 0.f; }

    // Pad rows of S (n >= N_NODES, n < NPAD) hold finite garbage; results
    // are discarded by the masked store. T2t rows 42,43 and cols 1806,1807
    // are zero, so the branch-free j-loop and padded-K tail are exact.
    const float* s0 = S + (size_t)n0 * SP;
    const float* s1 = S + (size_t)n1 * SP;
    for (int ki = kbeg; ki < kend; ki += 4) {
        float4 a = *(const float4*)(s0 + ki);
        float4 b = *(const float4*)(s1 + ki);
        #pragma unroll
        for (int j = 0; j < 11; ++j) {
            float4 t = *(const float4*)(T2t + (size_t)(w + 4 * j) * SP + ki);
            acc0[j] += a.x * t.x + a.y * t.y + a.z * t.z + a.w * t.w;
            acc1[j] += b.x * t.x + b.y * t.y + b.z * t.z + b.w * t.w;
        }
    }
    float* dst = aggP + (size_t)blockIdx.y * (N_NODES * D);
    #pragma unroll
    for (int j = 0; j < 11; ++j) {
        int o = w + 4 * j;
        if (o < D) {
            if (n0 < N_NODES) dst[(size_t)n0 * D + o] = acc0[j];
            if (n1 < N_NODES) dst[(size_t)n1 * D + o] = acc1[j];
        }
    }
}

// Elementwise: m[n,o] = relu(sum_ks aggP + out_in + conv_b)  (coalesced)
__global__ __launch_bounds__(256) void k_red(
        const float* __restrict__ aggP, const float* __restrict__ out_in,
        const float* __restrict__ conv_b, float* __restrict__ m) {
    int idx = blockIdx.x * 256 + threadIdx.x;
    if (idx >= N_NODES * D) return;
    float a = 0.f;
    #pragma unroll
    for (int ks = 0; ks < KSPLIT; ++ks)
        a += aggP[(size_t)ks * (N_NODES * D) + idx];
    a += out_in[idx] + conv_b[idx % D];
    m[idx] = fmaxf(a, 0.f);
}

// out' = relu(m @ msg_w + msg_b) [+ nf if last]
__global__ __launch_bounds__(256) void k_out(
        const float* __restrict__ m, const float* __restrict__ nf,
        const float* __restrict__ msg_w, const float* __restrict__ msg_b,
        float* __restrict__ out_dst, int last) {
    __shared__ float s_m[MB * 45];               // stride 45: conflict-free
    const int nl = threadIdx.x & 63;
    const int w  = threadIdx.x >> 6;
    const int n  = blockIdx.x * MB + nl;
    const int jm = (w < 2) ? 11 : 10;

    if (n < N_NODES) {
        for (int j = 0; j < jm; ++j) {
            int o = w + 4 * j;
            s_m[nl * 45 + o] = m[(size_t)n * D + o];
        }
    }
    __syncthreads();
    if (n < N_NODES) {
        float a2[11];
        #pragma unroll
        for (int j = 0; j < 11; ++j) a2[j] = 0.f;
        for (int o2 = 0; o2 < D; ++o2) {
            float mv = s_m[nl * 45 + o2];
            #pragma unroll
            for (int j = 0; j < 11; ++j)
                if (w + 4 * j < D)
                    a2[j] = fmaf(mv, msg_w[o2 * D + w + 4 * j], a2[j]);
        }
        for (int j = 0; j < jm; ++j) {
            int p = w + 4 * j;
            if (p < D) {
                float v = fmaxf(a2[j] + msg_b[p], 0.f);
                if (last) v += nf[n * D + p];
                out_dst[(size_t)n * D + p] = v;
            }
        }
    }
}

extern "C" void kernel_launch(void* const* d_in, const int* in_sizes, int n_in,
                              void* d_out, int out_size, void* d_ws, size_t ws_size,
                              hipStream_t stream) {
    const float* nf    = (const float*)d_in[0];
    const float* ef    = (const float*)d_in[1];
    const int*   src   = (const int*)d_in[2];
    const int*   dst   = (const int*)d_in[3];
    const float* lin0w = (const float*)d_in[4];
    const float* lin0b = (const float*)d_in[5];
    const float* msgw  = (const float*)d_in[6];
    const float* msgb  = (const float*)d_in[7];
    const float* enw1  = (const float*)d_in[8];
    const float* enb1  = (const float*)d_in[9];
    const float* enw2  = (const float*)d_in[10];
    const float* enb2  = (const float*)d_in[11];
    const float* convb = (const float*)d_in[12];

    // ws layout (~130 MB)
    char* p = (char*)d_ws;
    auto alloc = [&](size_t bytes) -> char* {
        char* r = p; p += (bytes + 255) & ~(size_t)255; return r;
    };
    float* outA = (float*)alloc((size_t)N_NODES * D * 4);
    float* outB = (float*)alloc((size_t)N_NODES * D * 4);
    float* hp   = (float*)alloc((size_t)N_EDGES * HP * 4);
    float* T2t  = (float*)alloc((size_t)44 * SP * 4);
    float* Sbuf = (float*)alloc((size_t)NPAD * SP * 4);
    float* aggP = (float*)alloc((size_t)KSPLIT * N_NODES * D * 4);
    float* mbuf = (float*)alloc((size_t)N_NODES * D * 4);
    int* cnt    = (int*)alloc((N_NODES + 1) * 4);
    int* rowp   = (int*)alloc((N_NODES + 1) * 4);
    int* cur    = (int*)alloc((N_NODES + 1) * 4);
    int* srcp   = (int*)alloc((size_t)N_EDGES * 4);
    int* posb   = (int*)alloc((size_t)N_EDGES * 4);

    hipMemsetAsync(cnt, 0, (N_NODES + 1) * 4, stream);
    k_lin0<<<(N_NODES * D + 255) / 256, 256, 0, stream>>>(nf, lin0w, lin0b, outA);
    k_T2t<<<(44 * SP + 255) / 256, 256, 0, stream>>>(enw2, enb2, T2t);
    k_hist<<<(N_EDGES + 255) / 256, 256, 0, stream>>>(dst, cnt);
    k_scan<<<1, 1024, 0, stream>>>(cnt, rowp, cur);
    k_scatter<<<(N_EDGES + 255) / 256, 256, 0, stream>>>(dst, src, cur, srcp, posb);
    k_h<<<(N_EDGES * HP + 255) / 256, 256, 0, stream>>>(ef, enw1, enb1, posb, hp);

    const int atiles = NPAD / MB2;                 // 79
    const int otiles = (N_NODES + MB - 1) / MB;    // 157
    float* bufs[2] = {outA, outB};
    for (int s_i = 0; s_i < 6; ++s_i) {
        const float* cin = bufs[s_i % 2];
        float* cout = bufs[(s_i + 1) % 2];
        int last = (s_i == 5) ? 1 : 0;
        k_S<<<N_NODES / 4, 256, 0, stream>>>(hp, cin, srcp, rowp, Sbuf);
        k_agg_part<<<dim3(atiles, KSPLIT), 256, 0, stream>>>(Sbuf, T2t, aggP);
        k_red<<<(N_NODES * D + 255) / 256, 256, 0, stream>>>(aggP, cin, convb, mbuf);
        k_out<<<otiles, 256, 0, stream>>>(mbuf, nf, msgw, msgb,
                                          last ? (float*)d_out : cout, last);
    }
}

// Round 5
// 1134.488 us; speedup vs baseline: 2.2919x; 1.1584x over previous
//
#include <hip/hip_runtime.h>

// GatherModel: 6-step NNConv message passing, reformulated:
//   agg[n,o] = sum_{k,i} S[n,k,i] * T'[k,i,o]
//   S[n] = sum_{e: dst=n} h'[e] (x) out[src[e]]     (rank-1 outer products)
//   h'[e] = [relu(e_feat@en_w1+b1), 1]              (step-invariant, bias folded)
//   T'[k,i,o] = en_w2[k, i*42+o]; T'[42,i,o] = en_b2[i*42+o]
// R5: kill the wave-uniform 16B VMEM broadcast storms.
//   k_agg_part: T2t K-chunk staged in LDS (ds_read_b128 broadcast), 4 nodes
//   per thread -> 176 FMA : 4 VMEM : 11 DS per iter (VALU-bound).
//   k_S: per-wave LDS staging of hp (coalesced float4, no barriers).

#define N_NODES 10000
#define N_EDGES 160000
#define D 42
#define DE 10
#define KH 43          // 42 + bias row
#define HP 44          // h row stride (11 x float4)
#define KI 1806        // 43*42
#define SP 1808        // S / T2t row stride
#define KSPLIT 16
#define KRANGE 116     // 15*116 + 68 = 1808, %4==0
#define MB4 256        // nodes per k_agg_part block (4 per thread)
#define NPAD 10240     // S rows padded to 40*256
#define MB 64          // nodes per k_out block
#define SCAP 32        // edges staged per k_S chunk (per wave)

__global__ __launch_bounds__(256) void k_lin0(const float* __restrict__ nf,
        const float* __restrict__ w, const float* __restrict__ b,
        float* __restrict__ out) {
    int idx = blockIdx.x * 256 + threadIdx.x;
    if (idx >= N_NODES * D) return;
    int n = idx / D, j = idx % D;
    const float* row = nf + n * D;
    float acc = b[j];
    #pragma unroll
    for (int i = 0; i < D; ++i) acc = fmaf(row[i], w[i * D + j], acc);
    out[idx] = fmaxf(acc, 0.f);
}

// T2t[o][ki] padded to 44 rows; rows 42,43 = 0 and pad cols (1806,1807) = 0
__global__ __launch_bounds__(256) void k_T2t(const float* __restrict__ w2,
        const float* __restrict__ b2, float* __restrict__ T2t) {
    int idx = blockIdx.x * 256 + threadIdx.x;
    if (idx >= 44 * SP) return;
    int o = idx / SP, ki = idx % SP;
    float v = 0.f;
    if (ki < KI && o < D) {
        int k = ki / D, i = ki % D;
        v = (k < D) ? w2[k * (D * D) + i * D + o] : b2[i * D + o];
    }
    T2t[idx] = v;
}

__global__ __launch_bounds__(256) void k_hist(const int* __restrict__ dst,
        int* __restrict__ cnt) {
    int e = blockIdx.x * 256 + threadIdx.x;
    if (e < N_EDGES) atomicAdd(&cnt[dst[e]], 1);
}

__global__ __launch_bounds__(1024) void k_scan(const int* __restrict__ cnt,
        int* __restrict__ row_ptr, int* __restrict__ cursor) {
    __shared__ int buf[1024];
    __shared__ int s_run;
    const int t = threadIdx.x;
    if (t == 0) s_run = 0;
    __syncthreads();
    for (int base = 0; base < N_NODES; base += 1024) {
        int v = (base + t < N_NODES) ? cnt[base + t] : 0;
        buf[t] = v;
        __syncthreads();
        for (int off = 1; off < 1024; off <<= 1) {
            int add = (t >= off) ? buf[t - off] : 0;
            __syncthreads();
            buf[t] += add;
            __syncthreads();
        }
        int excl = buf[t] - v;
        if (base + t < N_NODES) {
            int val = s_run + excl;
            row_ptr[base + t] = val;
            cursor[base + t]  = val;
        }
        __syncthreads();
        if (t == 0) s_run += buf[1023];
        __syncthreads();
    }
    if (t == 0) { row_ptr[N_NODES] = s_run; cursor[N_NODES] = s_run; }
}

__global__ __launch_bounds__(256) void k_scatter(const int* __restrict__ dst,
        const int* __restrict__ src, int* __restrict__ cursor,
        int* __restrict__ srcp, int* __restrict__ pos) {
    int e = blockIdx.x * 256 + threadIdx.x;
    if (e < N_EDGES) {
        int p = atomicAdd(&cursor[dst[e]], 1);
        pos[e] = p;
        srcp[p] = src[e];
    }
}

// h' in permuted (CSR) order: hp[pos[e]] = [relu(ef@w1+b1), 1, 0]
__global__ __launch_bounds__(256) void k_h(const float* __restrict__ ef,
        const float* __restrict__ w1, const float* __restrict__ b1,
        const int* __restrict__ pos, float* __restrict__ hp) {
    int idx = blockIdx.x * 256 + threadIdx.x;
    if (idx >= N_EDGES * HP) return;
    int e = idx / HP, j = idx % HP;
    float v;
    if (j < D) {
        const float* row = ef + e * DE;
        float acc = b1[j];
        #pragma unroll
        for (int i = 0; i < DE; ++i) acc = fmaf(row[i], w1[i * D + j], acc);
        v = fmaxf(acc, 0.f);
    } else {
        v = (j == D) ? 1.0f : 0.0f;
    }
    hp[(size_t)pos[e] * HP + j] = v;
}

// One wave per node. Per chunk of <=SCAP edges: stage hp rows into this
// wave's private LDS slice (coalesced float4), then consume via broadcast
// ds_read_b128. No __syncthreads: LDS ops of one wave complete in order;
// explicit lgkmcnt(0) covers write->read visibility.
__global__ __launch_bounds__(256) void k_S(
        const float* __restrict__ hp, const float* __restrict__ out_in,
        const int* __restrict__ srcp, const int* __restrict__ row_ptr,
        float* __restrict__ S) {
    __shared__ float sh[4 * SCAP * HP];          // 22.5 KB
    const int wv = threadIdx.x >> 6;
    const int l = threadIdx.x & 63;
    const int node = blockIdx.x * 4 + wv;
    const bool act = (l < D);
    float* mysh = sh + wv * (SCAP * HP);

    float acc[HP];
    #pragma unroll
    for (int k = 0; k < HP; ++k) acc[k] = 0.f;
    const int beg = row_ptr[node], end = row_ptr[node + 1];

    for (int base = beg; base < end; base += SCAP) {
        const int cnt = min(SCAP, end - base);
        const int nf4 = cnt * (HP / 4);
        for (int f = l; f < nf4; f += 64) {
            float4 v = *(const float4*)(hp + (size_t)base * HP + f * 4);
            *(float4*)&mysh[f * 4] = v;
        }
        asm volatile("s_waitcnt lgkmcnt(0)" ::: "memory");
        float xc = act ? out_in[srcp[base] * D + l] : 0.f;
        for (int j = 0; j < cnt; ++j) {
            float xn = 0.f;
            if (j + 1 < cnt && act) xn = out_in[srcp[base + j + 1] * D + l];
            #pragma unroll
            for (int m = 0; m < HP / 4; ++m) {
                float4 q = *(const float4*)&mysh[j * HP + m * 4];
                acc[4 * m + 0] = fmaf(q.x, xc, acc[4 * m + 0]);
                acc[4 * m + 1] = fmaf(q.y, xc, acc[4 * m + 1]);
                acc[4 * m + 2] = fmaf(q.z, xc, acc[4 * m + 2]);
                acc[4 * m + 3] = fmaf(q.w, xc, acc[4 * m + 3]);
            }
            xc = xn;
        }
    }
    if (act) {
        #pragma unroll
        for (int k = 0; k < KH; ++k)
            S[(size_t)node * SP + k * D + l] = acc[k];
    }
}

// Partial GEMM: aggP[ks][n][o] = sum_{ki in split} S[n][ki] * T2t[o][ki]
// T2t chunk staged in LDS; 4 nodes/thread -> 176 FMA : 4 VMEM : 11 DS.
__global__ __launch_bounds__(256) void k_agg_part(
        const float* __restrict__ S, const float* __restrict__ T2t,
        float* __restrict__ aggP) {
    __shared__ float s_t[44 * KRANGE];           // 20.4 KB
    const int t = threadIdx.x;
    const int nl = t & 63;
    const int w  = t >> 6;                       // o = w + 4j
    const int n0 = blockIdx.x * MB4 + nl;        // +0,64,128,192
    const int kbeg = blockIdx.y * KRANGE;
    const int KR = min(KRANGE, SP - kbeg);       // 116 or 68

    // stage T2t[0..43][kbeg..kbeg+KR) -> LDS (zero-padded source)
    const int nf4 = 44 * (KR / 4);
    const int f4row = KR / 4;
    for (int f = t; f < nf4; f += 256) {
        int row = f / f4row, c4 = f % f4row;
        float4 v = *(const float4*)(T2t + (size_t)row * SP + kbeg + c4 * 4);
        *(float4*)&s_t[row * KRANGE + c4 * 4] = v;
    }
    __syncthreads();

    float acc0[11], acc1[11], acc2[11], acc3[11];
    #pragma unroll
    for (int j = 0; j < 11; ++j) {
        acc0[j] = 0.f; acc1[j] = 0.f; acc2[j] = 0.f; acc3[j] = 0.f;
    }
    // Pad rows (n >= N_NODES) read finite garbage; stores are masked.
    const float* s0 = S + (size_t)n0 * SP + kbeg;
    const float* s1 = s0 + (size_t)64 * SP;
    const float* s2 = s0 + (size_t)128 * SP;
    const float* s3 = s0 + (size_t)192 * SP;
    for (int kil = 0; kil < KR; kil += 4) {
        float4 a = *(const float4*)(s0 + kil);
        float4 b = *(const float4*)(s1 + kil);
        float4 c = *(const float4*)(s2 + kil);
        float4 d = *(const float4*)(s3 + kil);
        #pragma unroll
        for (int j = 0; j < 11; ++j) {
            float4 tt = *(const float4*)&s_t[(w + 4 * j) * KRANGE + kil];
            acc0[j] += a.x * tt.x + a.y * tt.y + a.z * tt.z + a.w * tt.w;
            acc1[j] += b.x * tt.x + b.y * tt.y + b.z * tt.z + b.w * tt.w;
            acc2[j] += c.x * tt.x + c.y * tt.y + c.z * tt.z + c.w * tt.w;
            acc3[j] += d.x * tt.x + d.y * tt.y + d.z * tt.z + d.w * tt.w;
        }
    }
    float* dstp = aggP + (size_t)blockIdx.y * (N_NODES * D);
    #pragma unroll
    for (int j = 0; j < 11; ++j) {
        int o = w + 4 * j;
        if (o < D) {
            if (n0 < N_NODES)       dstp[(size_t)n0 * D + o] = acc0[j];
            if (n0 + 64 < N_NODES)  dstp[(size_t)(n0 + 64) * D + o] = acc1[j];
            if (n0 + 128 < N_NODES) dstp[(size_t)(n0 + 128) * D + o] = acc2[j];
            if (n0 + 192 < N_NODES) dstp[(size_t)(n0 + 192) * D + o] = acc3[j];
        }
    }
}

// Elementwise: m[n,o] = relu(sum_ks aggP + out_in + conv_b)  (coalesced)
__global__ __launch_bounds__(256) void k_red(
        const float* __restrict__ aggP, const float* __restrict__ out_in,
        const float* __restrict__ conv_b, float* __restrict__ m) {
    int idx = blockIdx.x * 256 + threadIdx.x;
    if (idx >= N_NODES * D) return;
    float a = 0.f;
    #pragma unroll
    for (int ks = 0; ks < KSPLIT; ++ks)
        a += aggP[(size_t)ks * (N_NODES * D) + idx];
    a += out_in[idx] + conv_b[idx % D];
    m[idx] = fmaxf(a, 0.f);
}

// out' = relu(m @ msg_w + msg_b) [+ nf if last]
__global__ __launch_bounds__(256) void k_out(
        const float* __restrict__ m, const float* __restrict__ nf,
        const float* __restrict__ msg_w, const float* __restrict__ msg_b,
        float* __restrict__ out_dst, int last) {
    __shared__ float s_m[MB * 45];               // stride 45: conflict-free
    const int nl = threadIdx.x & 63;
    const int w  = threadIdx.x >> 6;
    const int n  = blockIdx.x * MB + nl;
    const int jm = (w < 2) ? 11 : 10;

    if (n < N_NODES) {
        for (int j = 0; j < jm; ++j) {
            int o = w + 4 * j;
            s_m[nl * 45 + o] = m[(size_t)n * D + o];
        }
    }
    __syncthreads();
    if (n < N_NODES) {
        float a2[11];
        #pragma unroll
        for (int j = 0; j < 11; ++j) a2[j] = 0.f;
        for (int o2 = 0; o2 < D; ++o2) {
            float mv = s_m[nl * 45 + o2];
            #pragma unroll
            for (int j = 0; j < 11; ++j)
                if (w + 4 * j < D)
                    a2[j] = fmaf(mv, msg_w[o2 * D + w + 4 * j], a2[j]);
        }
        for (int j = 0; j < jm; ++j) {
            int p = w + 4 * j;
            if (p < D) {
                float v = fmaxf(a2[j] + msg_b[p], 0.f);
                if (last) v += nf[n * D + p];
                out_dst[(size_t)n * D + p] = v;
            }
        }
    }
}

extern "C" void kernel_launch(void* const* d_in, const int* in_sizes, int n_in,
                              void* d_out, int out_size, void* d_ws, size_t ws_size,
                              hipStream_t stream) {
    const float* nf    = (const float*)d_in[0];
    const float* ef    = (const float*)d_in[1];
    const int*   src   = (const int*)d_in[2];
    const int*   dst   = (const int*)d_in[3];
    const float* lin0w = (const float*)d_in[4];
    const float* lin0b = (const float*)d_in[5];
    const float* msgw  = (const float*)d_in[6];
    const float* msgb  = (const float*)d_in[7];
    const float* enw1  = (const float*)d_in[8];
    const float* enb1  = (const float*)d_in[9];
    const float* enw2  = (const float*)d_in[10];
    const float* enb2  = (const float*)d_in[11];
    const float* convb = (const float*)d_in[12];

    // ws layout (~135 MB)
    char* p = (char*)d_ws;
    auto alloc = [&](size_t bytes) -> char* {
        char* r = p; p += (bytes + 255) & ~(size_t)255; return r;
    };
    float* outA = (float*)alloc((size_t)N_NODES * D * 4);
    float* outB = (float*)alloc((size_t)N_NODES * D * 4);
    float* hp   = (float*)alloc((size_t)N_EDGES * HP * 4);
    float* T2t  = (float*)alloc((size_t)44 * SP * 4);
    float* Sbuf = (float*)alloc((size_t)NPAD * SP * 4);
    float* aggP = (float*)alloc((size_t)KSPLIT * N_NODES * D * 4);
    float* mbuf = (float*)alloc((size_t)N_NODES * D * 4);
    int* cnt    = (int*)alloc((N_NODES + 1) * 4);
    int* rowp   = (int*)alloc((N_NODES + 1) * 4);
    int* cur    = (int*)alloc((N_NODES + 1) * 4);
    int* srcp   = (int*)alloc((size_t)N_EDGES * 4);
    int* posb   = (int*)alloc((size_t)N_EDGES * 4);

    hipMemsetAsync(cnt, 0, (N_NODES + 1) * 4, stream);
    k_lin0<<<(N_NODES * D + 255) / 256, 256, 0, stream>>>(nf, lin0w, lin0b, outA);
    k_T2t<<<(44 * SP + 255) / 256, 256, 0, stream>>>(enw2, enb2, T2t);
    k_hist<<<(N_EDGES + 255) / 256, 256, 0, stream>>>(dst, cnt);
    k_scan<<<1, 1024, 0, stream>>>(cnt, rowp, cur);
    k_scatter<<<(N_EDGES + 255) / 256, 256, 0, stream>>>(dst, src, cur, srcp, posb);
    k_h<<<(N_EDGES * HP + 255) / 256, 256, 0, stream>>>(ef, enw1, enb1, posb, hp);

    const int atiles = NPAD / MB4;                 // 40
    const int otiles = (N_NODES + MB - 1) / MB;    // 157
    float* bufs[2] = {outA, outB};
    for (int s_i = 0; s_i < 6; ++s_i) {
        const float* cin = bufs[s_i % 2];
        float* cout = bufs[(s_i + 1) % 2];
        int last = (s_i == 5) ? 1 : 0;
        k_S<<<N_NODES / 4, 256, 0, stream>>>(hp, cin, srcp, rowp, Sbuf);
        k_agg_part<<<dim3(atiles, KSPLIT), 256, 0, stream>>>(Sbuf, T2t, aggP);
        k_red<<<(N_NODES * D + 255) / 256, 256, 0, stream>>>(aggP, cin, convb, mbuf);
        k_out<<<otiles, 256, 0, stream>>>(mbuf, nf, msgw, msgb,
                                          last ? (float*)d_out : cout, last);
    }
}

// Round 6
// 651.799 us; speedup vs baseline: 3.9892x; 1.7405x over previous
//
#include <hip/hip_runtime.h>
#include <hip/hip_bf16.h>

// GatherModel: 6-step NNConv message passing, reformulated:
//   agg[n,o] = sum_{ki} S[n,ki] * T'[ki,o]   (ki = k*42+i, K padded to 1824)
//   S[n] = sum_{e: dst=n} h'[e] (x) out[src[e]]
//   h'[e] = [relu(e_feat@en_w1+b1), 1]       (step-invariant)
// R6: GEMM on matrix cores. S and T' in bf16; T' pre-packed into MFMA
// B-fragment order with the SAME k<->(group,elem) map as the A-side row-major
// read (any bijection works if A/B agree; C/D layout is the m89-verified
// col=lane&15, row=(lane>>4)*4+reg). K-split x8, 1-wave blocks, grid 640x8.
// k_S: depth-2 x-gather prefetch + bf16 stores.

#define N_NODES 10000
#define N_EDGES 160000
#define D 42
#define DE 10
#define KH 43          // 42 + bias row
#define HP 44          // h row stride (11 x float4)
#define KI 1806        // 43*42
#define KP 1824        // padded K: 57 * 32
#define NKSTEP 57      // K-steps of 32
#define SPLITS 8
#define NPAD 10240     // S rows padded to 640*16
#define MB 64          // nodes per k_out block
#define SCAP 32        // edges staged per k_S chunk (per wave)

typedef __attribute__((ext_vector_type(8))) short short8;
typedef __attribute__((ext_vector_type(4))) float f32x4;

__global__ __launch_bounds__(256) void k_lin0(const float* __restrict__ nf,
        const float* __restrict__ w, const float* __restrict__ b,
        float* __restrict__ out) {
    int idx = blockIdx.x * 256 + threadIdx.x;
    if (idx >= N_NODES * D) return;
    int n = idx / D, j = idx % D;
    const float* row = nf + n * D;
    float acc = b[j];
    #pragma unroll
    for (int i = 0; i < D; ++i) acc = fmaf(row[i], w[i * D + j], acc);
    out[idx] = fmaxf(acc, 0.f);
}

// B-fragments: Bfr[((nt*57 + ks)*64 + lane)*8 + j] = bf16(T'[k][col]),
// col = nt*16 + (lane&15), k = ks*32 + (lane>>4)*8 + j. Zero outside range.
__global__ __launch_bounds__(256) void k_T2B(const float* __restrict__ w2,
        const float* __restrict__ b2, __hip_bfloat16* __restrict__ Bfr) {
    int idx = blockIdx.x * 256 + threadIdx.x;
    if (idx >= 3 * NKSTEP * 64 * 8) return;
    int j = idx & 7, lane = (idx >> 3) & 63;
    int ks = (idx >> 9) % NKSTEP, nt = idx / (NKSTEP * 512);
    int col = nt * 16 + (lane & 15);
    int k = ks * 32 + ((lane >> 4) * 8) + j;
    float v = 0.f;
    if (col < D && k < KI) {
        int kk = k / D, ii = k % D;
        v = (kk < D) ? w2[kk * (D * D) + ii * D + col] : b2[ii * D + col];
    }
    Bfr[idx] = __float2bfloat16(v);
}

__global__ __launch_bounds__(256) void k_hist(const int* __restrict__ dst,
        int* __restrict__ cnt) {
    int e = blockIdx.x * 256 + threadIdx.x;
    if (e < N_EDGES) atomicAdd(&cnt[dst[e]], 1);
}

__global__ __launch_bounds__(1024) void k_scan(const int* __restrict__ cnt,
        int* __restrict__ row_ptr, int* __restrict__ cursor) {
    __shared__ int buf[1024];
    __shared__ int s_run;
    const int t = threadIdx.x;
    if (t == 0) s_run = 0;
    __syncthreads();
    for (int base = 0; base < N_NODES; base += 1024) {
        int v = (base + t < N_NODES) ? cnt[base + t] : 0;
        buf[t] = v;
        __syncthreads();
        for (int off = 1; off < 1024; off <<= 1) {
            int add = (t >= off) ? buf[t - off] : 0;
            __syncthreads();
            buf[t] += add;
            __syncthreads();
        }
        int excl = buf[t] - v;
        if (base + t < N_NODES) {
            int val = s_run + excl;
            row_ptr[base + t] = val;
            cursor[base + t]  = val;
        }
        __syncthreads();
        if (t == 0) s_run += buf[1023];
        __syncthreads();
    }
    if (t == 0) { row_ptr[N_NODES] = s_run; cursor[N_NODES] = s_run; }
}

__global__ __launch_bounds__(256) void k_scatter(const int* __restrict__ dst,
        const int* __restrict__ src, int* __restrict__ cursor,
        int* __restrict__ srcp, int* __restrict__ pos) {
    int e = blockIdx.x * 256 + threadIdx.x;
    if (e < N_EDGES) {
        int p = atomicAdd(&cursor[dst[e]], 1);
        pos[e] = p;
        srcp[p] = src[e];
    }
}

// h' in permuted (CSR) order: hp[pos[e]] = [relu(ef@w1+b1), 1, 0]
__global__ __launch_bounds__(256) void k_h(const float* __restrict__ ef,
        const float* __restrict__ w1, const float* __restrict__ b1,
        const int* __restrict__ pos, float* __restrict__ hp) {
    int idx = blockIdx.x * 256 + threadIdx.x;
    if (idx >= N_EDGES * HP) return;
    int e = idx / HP, j = idx % HP;
    float v;
    if (j < D) {
        const float* row = ef + e * DE;
        float acc = b1[j];
        #pragma unroll
        for (int i = 0; i < DE; ++i) acc = fmaf(row[i], w1[i * D + j], acc);
        v = fmaxf(acc, 0.f);
    } else {
        v = (j == D) ? 1.0f : 0.0f;
    }
    hp[(size_t)pos[e] * HP + j] = v;
}

// One wave per node; hp staged per-wave in LDS (no barriers, same-wave
// ordering + lgkmcnt(0)); x gathers depth-2 prefetched; bf16 S output,
// row-major [n][KP] with pad cols 1806..1823 zeroed.
__global__ __launch_bounds__(256) void k_S(
        const float* __restrict__ hp, const float* __restrict__ out_in,
        const int* __restrict__ srcp, const int* __restrict__ row_ptr,
        __hip_bfloat16* __restrict__ S) {
    __shared__ float sh[4 * SCAP * HP];          // 22.5 KB
    const int wv = threadIdx.x >> 6;
    const int l = threadIdx.x & 63;
    const int node = blockIdx.x * 4 + wv;
    const bool act = (l < D);
    float* mysh = sh + wv * (SCAP * HP);

    float acc[HP];
    #pragma unroll
    for (int k = 0; k < HP; ++k) acc[k] = 0.f;
    const int beg = row_ptr[node], end = row_ptr[node + 1];

    for (int base = beg; base < end; base += SCAP) {
        const int cnt = min(SCAP, end - base);
        const int nf4 = cnt * (HP / 4);
        for (int f = l; f < nf4; f += 64) {
            float4 v = *(const float4*)(hp + (size_t)base * HP + f * 4);
            *(float4*)&mysh[f * 4] = v;
        }
        asm volatile("s_waitcnt lgkmcnt(0)" ::: "memory");
        float x0 = 0.f, x1 = 0.f;
        if (act) {
            x0 = out_in[srcp[base] * D + l];
            if (cnt > 1) x1 = out_in[srcp[base + 1] * D + l];
        }
        for (int j = 0; j < cnt; ++j) {
            float x2 = 0.f;
            if (act && j + 2 < cnt) x2 = out_in[srcp[base + j + 2] * D + l];
            #pragma unroll
            for (int m = 0; m < HP / 4; ++m) {
                float4 q = *(const float4*)&mysh[j * HP + m * 4];
                acc[4 * m + 0] = fmaf(q.x, x0, acc[4 * m + 0]);
                acc[4 * m + 1] = fmaf(q.y, x0, acc[4 * m + 1]);
                acc[4 * m + 2] = fmaf(q.z, x0, acc[4 * m + 2]);
                acc[4 * m + 3] = fmaf(q.w, x0, acc[4 * m + 3]);
            }
            x0 = x1; x1 = x2;
        }
    }
    if (act) {
        #pragma unroll
        for (int k = 0; k < KH; ++k)
            S[(size_t)node * KP + k * D + l] = __float2bfloat16(acc[k]);
    } else if (l < 60) {
        // pad cols 1806..1823 (= 1764 + l for l in [42,60))
        S[(size_t)node * KP + 1764 + l] = __float2bfloat16(0.f);
    }
}

// MFMA GEMM: aggP[sp][n][c] (c<48) partial over K-steps [ks0,ks1).
// A: lane l reads S[n0+(l&15)][ks*32 + (l>>4)*8 .. +7] (16B contiguous).
// B: pre-packed fragments, lane-contiguous 16B (perfectly coalesced).
// D: col = lane&15 (+16*nt), row(node) = n0 + (lane>>4)*4 + reg.
__global__ __launch_bounds__(64) void k_agg_mfma(
        const __hip_bfloat16* __restrict__ Sb,
        const __hip_bfloat16* __restrict__ Bfr,
        float* __restrict__ aggP) {
    const int l  = threadIdx.x;
    const int mt = blockIdx.x;                  // 0..639
    const int sp = blockIdx.y;                  // 0..SPLITS-1
    const int ks0 = (sp * NKSTEP) / SPLITS;
    const int ks1 = ((sp + 1) * NKSTEP) / SPLITS;
    const int n0 = mt * 16;

    f32x4 acc0 = {0.f, 0.f, 0.f, 0.f};
    f32x4 acc1 = {0.f, 0.f, 0.f, 0.f};
    f32x4 acc2 = {0.f, 0.f, 0.f, 0.f};

    const short* srow = (const short*)Sb
        + (size_t)(n0 + (l & 15)) * KP + ((l >> 4) * 8);
    const short* bbase = (const short*)Bfr + (size_t)l * 8;

    for (int ks = ks0; ks < ks1; ++ks) {
        short8 a  = *(const short8*)(srow + (size_t)ks * 32);
        short8 b0 = *(const short8*)(bbase + (size_t)(0 * NKSTEP + ks) * 512);
        short8 b1 = *(const short8*)(bbase + (size_t)(1 * NKSTEP + ks) * 512);
        short8 b2 = *(const short8*)(bbase + (size_t)(2 * NKSTEP + ks) * 512);
        acc0 = __builtin_amdgcn_mfma_f32_16x16x32_bf16(a, b0, acc0, 0, 0, 0);
        acc1 = __builtin_amdgcn_mfma_f32_16x16x32_bf16(a, b1, acc1, 0, 0, 0);
        acc2 = __builtin_amdgcn_mfma_f32_16x16x32_bf16(a, b2, acc2, 0, 0, 0);
    }

    float* dstp = aggP + (size_t)sp * ((size_t)NPAD * 48);
    const int row = n0 + ((l >> 4) * 4);
    const int col = l & 15;
    #pragma unroll
    for (int r = 0; r < 4; ++r) {
        dstp[(size_t)(row + r) * 48 + col]      = acc0[r];
        dstp[(size_t)(row + r) * 48 + 16 + col] = acc1[r];
        dstp[(size_t)(row + r) * 48 + 32 + col] = acc2[r];
    }
}

// m[n,o] = relu(sum_sp aggP[sp][n][o] + out_in[n,o] + conv_b[o])
__global__ __launch_bounds__(256) void k_red(
        const float* __restrict__ aggP, const float* __restrict__ out_in,
        const float* __restrict__ conv_b, float* __restrict__ m) {
    int idx = blockIdx.x * 256 + threadIdx.x;
    if (idx >= N_NODES * D) return;
    int n = idx / D, o = idx % D;
    float a = 0.f;
    #pragma unroll
    for (int sp = 0; sp < SPLITS; ++sp)
        a += aggP[(size_t)sp * ((size_t)NPAD * 48) + (size_t)n * 48 + o];
    a += out_in[idx] + conv_b[o];
    m[idx] = fmaxf(a, 0.f);
}

// out' = relu(m @ msg_w + msg_b) [+ nf if last]
__global__ __launch_bounds__(256) void k_out(
        const float* __restrict__ m, const float* __restrict__ nf,
        const float* __restrict__ msg_w, const float* __restrict__ msg_b,
        float* __restrict__ out_dst, int last) {
    __shared__ float s_m[MB * 45];               // stride 45: conflict-free
    const int nl = threadIdx.x & 63;
    const int w  = threadIdx.x >> 6;
    const int n  = blockIdx.x * MB + nl;
    const int jm = (w < 2) ? 11 : 10;

    if (n < N_NODES) {
        for (int j = 0; j < jm; ++j) {
            int o = w + 4 * j;
            s_m[nl * 45 + o] = m[(size_t)n * D + o];
        }
    }
    __syncthreads();
    if (n < N_NODES) {
        float a2[11];
        #pragma unroll
        for (int j = 0; j < 11; ++j) a2[j] = 0.f;
        for (int o2 = 0; o2 < D; ++o2) {
            float mv = s_m[nl * 45 + o2];
            #pragma unroll
            for (int j = 0; j < 11; ++j)
                if (w + 4 * j < D)
                    a2[j] = fmaf(mv, msg_w[o2 * D + w + 4 * j], a2[j]);
        }
        for (int j = 0; j < jm; ++j) {
            int p = w + 4 * j;
            if (p < D) {
                float v = fmaxf(a2[j] + msg_b[p], 0.f);
                if (last) v += nf[n * D + p];
                out_dst[(size_t)n * D + p] = v;
            }
        }
    }
}

extern "C" void kernel_launch(void* const* d_in, const int* in_sizes, int n_in,
                              void* d_out, int out_size, void* d_ws, size_t ws_size,
                              hipStream_t stream) {
    const float* nf    = (const float*)d_in[0];
    const float* ef    = (const float*)d_in[1];
    const int*   src   = (const int*)d_in[2];
    const int*   dst   = (const int*)d_in[3];
    const float* lin0w = (const float*)d_in[4];
    const float* lin0b = (const float*)d_in[5];
    const float* msgw  = (const float*)d_in[6];
    const float* msgb  = (const float*)d_in[7];
    const float* enw1  = (const float*)d_in[8];
    const float* enb1  = (const float*)d_in[9];
    const float* enw2  = (const float*)d_in[10];
    const float* enb2  = (const float*)d_in[11];
    const float* convb = (const float*)d_in[12];

    // ws layout (~90 MB)
    char* p = (char*)d_ws;
    auto alloc = [&](size_t bytes) -> char* {
        char* r = p; p += (bytes + 255) & ~(size_t)255; return r;
    };
    float* outA = (float*)alloc((size_t)N_NODES * D * 4);
    float* outB = (float*)alloc((size_t)N_NODES * D * 4);
    float* hp   = (float*)alloc((size_t)N_EDGES * HP * 4);
    __hip_bfloat16* Sb  = (__hip_bfloat16*)alloc((size_t)NPAD * KP * 2);
    __hip_bfloat16* Bfr = (__hip_bfloat16*)alloc((size_t)3 * NKSTEP * 64 * 8 * 2);
    float* aggP = (float*)alloc((size_t)SPLITS * NPAD * 48 * 4);
    float* mbuf = (float*)alloc((size_t)N_NODES * D * 4);
    int* cnt    = (int*)alloc((N_NODES + 1) * 4);
    int* rowp   = (int*)alloc((N_NODES + 1) * 4);
    int* cur    = (int*)alloc((N_NODES + 1) * 4);
    int* srcp   = (int*)alloc((size_t)N_EDGES * 4);
    int* posb   = (int*)alloc((size_t)N_EDGES * 4);

    hipMemsetAsync(cnt, 0, (N_NODES + 1) * 4, stream);
    k_lin0<<<(N_NODES * D + 255) / 256, 256, 0, stream>>>(nf, lin0w, lin0b, outA);
    k_T2B<<<(3 * NKSTEP * 64 * 8 + 255) / 256, 256, 0, stream>>>(enw2, enb2, Bfr);
    k_hist<<<(N_EDGES + 255) / 256, 256, 0, stream>>>(dst, cnt);
    k_scan<<<1, 1024, 0, stream>>>(cnt, rowp, cur);
    k_scatter<<<(N_EDGES + 255) / 256, 256, 0, stream>>>(dst, src, cur, srcp, posb);
    k_h<<<(N_EDGES * HP + 255) / 256, 256, 0, stream>>>(ef, enw1, enb1, posb, hp);

    const int mtiles = NPAD / 16;                  // 640
    const int otiles = (N_NODES + MB - 1) / MB;    // 157
    float* bufs[2] = {outA, outB};
    for (int s_i = 0; s_i < 6; ++s_i) {
        const float* cin = bufs[s_i % 2];
        float* cout = bufs[(s_i + 1) % 2];
        int last = (s_i == 5) ? 1 : 0;
        k_S<<<N_NODES / 4, 256, 0, stream>>>(hp, cin, srcp, rowp, Sb);
        k_agg_mfma<<<dim3(mtiles, SPLITS), 64, 0, stream>>>(Sb, Bfr, aggP);
        k_red<<<(N_NODES * D + 255) / 256, 256, 0, stream>>>(aggP, cin, convb, mbuf);
        k_out<<<otiles, 256, 0, stream>>>(mbuf, nf, msgw, msgb,
                                          last ? (float*)d_out : cout, last);
    }
}